// Round 8
// baseline (7394022.656 us; speedup 1.0000x reference)
//
#include <hip/hip_runtime.h>
#include <hip/hip_bf16.h>

// LSTM decoder: B=512, H=1024, NCHAR=128, T=256.
// Round 8 = round-7 kernel (PASSED, 4660us) with ONE change-cluster: the
// ACQUIRE side of the per-step grid barrier. Cost model from r6/r7: each L2
// maintenance walk (wbl2/inv) ~0.55us, serialized per XCD. r7 still had 32
// per-block acquire-fence buffer_inv walks per XCD per step (~18us/step).
// New acquire: the elected last-arriver per XCD polls gCnt, does the ONE
// agent acquire fence (L2+L1 inv), then publishes a per-XCD epoch word via a
// plain store into its own (XCD-shared, write-through-L1) L2. Non-elected
// blocks spin on the epoch with sc0 (L1-bypass, L2-hit) loads -- no walks --
// then do a single sc-less buffer_inv (L1-only flash) before reading h.
// Bounded-spin fallback (poll gCnt + full threadfence) guarantees progress.
// Release side, census, election: byte-for-byte r7 (proven).

using bf16 = __hip_bfloat16;
typedef short bf16x8 __attribute__((ext_vector_type(8)));
typedef float f32x4  __attribute__((ext_vector_type(4)));
typedef float f32x16 __attribute__((ext_vector_type(16)));

static constexpr int BATCH = 512;
static constexpr int HID   = 1024;
static constexpr int NCH   = 128;
static constexpr int TLEN  = 256;
static constexpr int NP    = 4096;   // 4*HID

// workspace byte offsets
static constexpr size_t OFF_WP  = 0;                                // bf16 [4096][1024] fused W, rows permuted
static constexpr size_t OFF_WOB = OFF_WP  + (size_t)NP * HID * 2;   // bf16 [128][1024]
static constexpr size_t OFF_HB0 = OFF_WOB + (size_t)NCH * HID * 2;  // bf16 h buffer 0
static constexpr size_t OFF_HB1 = OFF_HB0 + (size_t)BATCH * HID * 2;
static constexpr size_t OFF_XP  = OFF_HB1 + (size_t)BATCH * HID * 2; // f32 [512][4096] x_part permuted
static constexpr size_t OFF_BAR = OFF_XP  + (size_t)BATCH * NP * 4;
// bar layout (u32 index; prep_misc zeroes [0,1024)):
//   [x*32]      x<8 : per-XCD population census
//   [8*32]          : census completion counter
//   [(16+x)*32] x<8 : per-XCD per-step arrival counters (monotone)
//   [24*32]         : global step counter gCnt (monotone)
//   [800+x*16]  x<8 : per-XCD epoch words (published via local-L2 store)

__device__ __forceinline__ float sigm(float x) { return 1.f / (1.f + __expf(-x)); }

// permuted gate-row index: row' = (j>>4)*64 + gate*16 + (j&15); decode n = gate*H + j
__device__ __forceinline__ int rowp_to_n(int rp) {
  int jg = rp >> 6, c = rp & 63;
  return (c >> 4) * HID + jg * 16 + (c & 15);
}

__global__ void prep_misc(const float* __restrict__ hid0, const float* __restrict__ wout,
                          bf16* __restrict__ hb0, bf16* __restrict__ wob,
                          unsigned* __restrict__ bar)
{
  int gid = blockIdx.x * blockDim.x + threadIdx.x;
  int stride = gridDim.x * blockDim.x;
  for (int i = gid; i < BATCH * HID; i += stride) hb0[i] = __float2bfloat16(hid0[i]);
  for (int i = gid; i < NCH * HID;  i += stride) wob[i] = __float2bfloat16(wout[i]);
  if (gid < 1024) bar[gid] = 0u;
}

__global__ void prep_wp(const float* __restrict__ W_ih, const float* __restrict__ W_hh,
                        bf16* __restrict__ wp)
{
  int gid = blockIdx.x * blockDim.x + threadIdx.x;
  int stride = gridDim.x * blockDim.x;
  for (int i = gid; i < NP * HID; i += stride) {
    int rp = i >> 10, k = i & 1023;
    int n = rowp_to_n(rp);
    float v = W_ih[(size_t)n * 1152 + 128 + k] + W_hh[(size_t)n * 1024 + k];
    wp[i] = __float2bfloat16(v);
  }
}

__global__ void prep_xp(const float* __restrict__ inp0, const float* __restrict__ W_ih,
                        const float* __restrict__ b_ih, const float* __restrict__ b_hh,
                        float* __restrict__ xp)
{
  int b = blockIdx.x;
  const float4* ip = (const float4*)(inp0 + b * NCH);
  for (int rp = threadIdx.x; rp < NP; rp += blockDim.x) {
    int n = rowp_to_n(rp);
    const float4* wr = (const float4*)(W_ih + (size_t)n * 1152);
    float acc = b_ih[n] + b_hh[n];
    #pragma unroll 8
    for (int q = 0; q < 32; ++q) {
      float4 a = ip[q], w = wr[q];
      acc += a.x * w.x + a.y * w.y + a.z * w.z + a.w * w.w;
    }
    xp[(size_t)b * NP + rp] = acc;
  }
}

__launch_bounds__(256, 1)
__global__ void lstm_main(const bf16* __restrict__ wp, const bf16* __restrict__ wob,
                          const float* __restrict__ xp, const float* __restrict__ cell0,
                          const float* __restrict__ bout,
                          bf16* __restrict__ hb0, bf16* __restrict__ hb1,
                          float* __restrict__ out, unsigned* __restrict__ bar)
{
  __shared__ bf16 wlds[64 * HID];        // 128 KB, xor-swizzled
  __shared__ float obuf[16][16][17];     // out tile x 16 buffered steps (+1 pad)
  __shared__ int s_pop[8];

  const int tid  = threadIdx.x;
  const int bx   = blockIdx.x;
  const int lane = tid & 63;
  const int wv   = tid >> 6;        // wave 0..3 (rows)
  const int bm   = bx >> 6;         // batch group 0..3 (128 rows)
  const int jg   = bx & 63;         // j group (16 h-cols -> 64 gate rows)
  const int wrow = bm * 128 + wv * 32;
  const int l31  = lane & 31;
  const int lhi  = lane >> 5;
  const bool low = (l31 < 16);
  const int jj   = lane & 15;
  const int jcol = jg * 16 + jj;

  // stage fused-W slice into LDS (swizzled: byte ^= (row&7)<<4)
  {
    const char* src = (const char*)(wp + (size_t)jg * 64 * HID);
    for (int it = tid; it < 8192; it += 256) {
      int r  = it >> 7;
      int kb = (it & 127) << 4;
      bf16x8 v = *(const bf16x8*)(src + r * 2048 + kb);
      *(bf16x8*)((char*)wlds + r * 2048 + (kb ^ ((r & 7) << 4))) = v;
    }
  }

  // x_part -> registers (constant acc init; C layout: col=lane&31, row=(q&3)+8*(q>>2)+4*lhi)
  f32x16 xpA, xpB;
  #pragma unroll
  for (int q = 0; q < 16; ++q) {
    int rr = (q & 3) + ((q >> 2) << 3) + (lhi << 2);
    const float* xr = xp + (size_t)(wrow + rr) * NP + jg * 64;
    xpA[q] = xr[l31];
    xpB[q] = xr[32 + l31];
  }

  // cell state -> registers. low half-lanes own rows {0-3,8-11}+4*lhi, high own +16.
  float creg[8];
  #pragma unroll
  for (int q = 0; q < 8; ++q) {
    int rr = (q & 3) + ((q >> 2) << 3) + (lhi << 2) + (low ? 0 : 16);
    creg[q] = cell0[(size_t)(wrow + rr) * HID + jcol];
  }

  const int omt = (bx >> 3) << 4;   // out-tile batch row base (32 tiles of 16)
  const int ont = (bx & 7) << 4;    // out-tile char col base (8 tiles of 16)
  const float bo = bout[ont + jj];

  // ---- one-time census: physical XCD id + per-XCD block population
  const int myx = __builtin_amdgcn_s_getreg(6164) & 7;  // HW_REG_XCC_ID (id=20,off=0,sz=4)
  if (tid == 0) {
    __hip_atomic_fetch_add(bar + (size_t)myx * 32, 1u, __ATOMIC_RELAXED, __HIP_MEMORY_SCOPE_AGENT);
    __threadfence();   // order pop-add before census-completion add
    __hip_atomic_fetch_add(bar + (size_t)8 * 32, 1u, __ATOMIC_RELEASE, __HIP_MEMORY_SCOPE_AGENT);
    int it = 0;
    while (__hip_atomic_load(bar + (size_t)8 * 32, __ATOMIC_RELAXED, __HIP_MEMORY_SCOPE_AGENT) < 256u) {
      __builtin_amdgcn_s_sleep(2);
      if ((++it & 255) == 0) __builtin_amdgcn_fence(__ATOMIC_ACQUIRE, "agent");
    }
  }
  __syncthreads();
  if (tid < 8)
    s_pop[tid] = (int)__hip_atomic_load(bar + (size_t)tid * 32, __ATOMIC_RELAXED, __HIP_MEMORY_SCOPE_AGENT);
  __syncthreads();
  int nx = 0, tot = 0;
  #pragma unroll
  for (int i = 0; i < 8; ++i) { nx += (s_pop[i] != 0) ? 1 : 0; tot += s_pop[i]; }
  const bool elect = (nx >= 2) && (tot == 256);   // degenerate -> all-flush (r7/r6 semantics)
  const unsigned mypop = (unsigned)s_pop[myx];
  const unsigned NF = elect ? (unsigned)nx : 256u;
  unsigned* const xcdCnt = bar + (size_t)(16 + myx) * 32;
  unsigned* const gCnt   = bar + (size_t)24 * 32;
  unsigned* const epochX = bar + (size_t)(800 + myx * 16);

  __syncthreads();

  for (int t = 0; t <= TLEN; ++t) {
    const bf16* __restrict__ hcur = (t & 1) ? hb1 : hb0;
    bf16* __restrict__ hnxt = (t & 1) ? hb0 : hb1;

    // out GEMM for step t-1 (uses h_t = hcur), wave 0 only; 16x16x1024 tile
    if (t >= 1 && wv == 0) {
      f32x4 oacc = {0.f, 0.f, 0.f, 0.f};
      const int kq = (lane >> 4) << 3;
      const bf16* ap = hcur + (size_t)(omt + jj) * HID + kq;
      const bf16* bp = wob + (size_t)(ont + jj) * HID + kq;
      #pragma unroll 8
      for (int ks = 0; ks < 32; ++ks) {
        bf16x8 av = *(const bf16x8*)(ap + ks * 32);
        bf16x8 bv = *(const bf16x8*)(bp + ks * 32);
        oacc = __builtin_amdgcn_mfma_f32_16x16x32_bf16(av, bv, oacc, 0, 0, 0);
      }
      const int slot = (t - 1) & 15;
      #pragma unroll
      for (int q = 0; q < 4; ++q)
        obuf[((lane >> 4) << 2) + q][jj][slot] = oacc[q] + bo;   // row=(l>>4)*4+q, col=jj
    }

    // flush 16 buffered output steps (coalesced 64B runs into [b][o][t] layout)
    if ((t & 15) == 0 && t >= 16) {
      __syncthreads();
      const int orow = tid >> 4, ocol = tid & 15;
      float* dst = out + ((size_t)(omt + orow) * NCH + (ont + ocol)) * TLEN + (t - 16);
      #pragma unroll
      for (int s = 0; s < 16; ++s) dst[s] = obuf[orow][ocol][s];
    }

    if (t == TLEN) break;

    // gates GEMM: [128x64] = x_part + h[128x1024] @ W'[64x1024]^T
    f32x16 accA = xpA, accB = xpB;
    {
      const bf16* ap = hcur + (size_t)(wrow + l31) * HID + (lhi << 3);
      const char* wb = (const char*)wlds;
      const int base0 = l31 * 2048;
      const int sxor  = (l31 & 7) << 4;
      const int kb4   = lhi << 4;
      #pragma unroll 8
      for (int ks = 0; ks < 64; ++ks) {
        bf16x8 av = *(const bf16x8*)(ap + ks * 16);
        const int ko = ((ks << 5) | kb4) ^ sxor;
        bf16x8 b0 = *(const bf16x8*)(wb + base0 + ko);
        bf16x8 b1 = *(const bf16x8*)(wb + base0 + 65536 + ko);
        accA = __builtin_amdgcn_mfma_f32_32x32x16_bf16(av, b0, accA, 0, 0, 0);
        accB = __builtin_amdgcn_mfma_f32_32x32x16_bf16(av, b1, accB, 0, 0, 0);
      }
    }

    // LSTM cell update. accA cols: i (l31<16) / f (l31>=16); accB: g / o.
    float s0[16], s1[16], u0[16], u1[16];
    #pragma unroll
    for (int q = 0; q < 16; ++q) {
      s0[q] = sigm(accA[q]);                       // sig(i) on low, sig(f) on high
      float a1 = accB[q];
      float sg = sigm(low ? 2.f * a1 : a1);
      s1[q] = low ? 2.f * sg - 1.f : sg;           // tanh(g) on low, sig(o) on high
    }
    #pragma unroll
    for (int q = 0; q < 16; ++q) {
      u0[q] = __shfl_xor(s0[q], 16);
      u1[q] = __shfl_xor(s1[q], 16);
    }
    #pragma unroll
    for (int q = 0; q < 8; ++q) {
      float fg  = low ? u0[q]         : s0[q + 8];
      float ig  = low ? s0[q] * s1[q] : u0[q + 8] * u1[q + 8];
      float og  = low ? u1[q]         : s1[q + 8];
      float cn  = fg * creg[q] + ig;
      creg[q] = cn;
      float hv = og * (2.f * sigm(2.f * cn) - 1.f);
      int rr = (q & 3) + ((q >> 2) << 3) + (lhi << 2) + (low ? 0 : 16);
      hnxt[(size_t)(wrow + rr) * HID + jcol] = __float2bfloat16(hv);
    }

    // ---- grid barrier: elected release (r7) + elected acquire (NEW) ----
    // syncthreads drains vmcnt -> all 4 waves' h stores are in this XCD's L2.
    __syncthreads();
    if (tid == 0) {
      unsigned old = __hip_atomic_fetch_add(xcdCnt, 1u, __ATOMIC_RELAXED, __HIP_MEMORY_SCOPE_AGENT);
      const bool lastx = !elect || (old == mypop * (unsigned)(t + 1) - 1u);
      if (lastx) {
        // last arriver on this XCD: all XCD-mates' stores are in this L2.
        __threadfence();   // buffer_wbl2: push them to the LLC (r7-proven)
        __hip_atomic_fetch_add(gCnt, 1u, __ATOMIC_RELEASE, __HIP_MEMORY_SCOPE_AGENT);
      }
      if (!elect) {
        // fallback: r7 shape -- every block polls gCnt
        const unsigned tgt = NF * (unsigned)(t + 1);
        int it = 0;
        while (__hip_atomic_load(gCnt, __ATOMIC_RELAXED, __HIP_MEMORY_SCOPE_AGENT) < tgt) {
          __builtin_amdgcn_s_sleep(2);
          if ((++it & 255) == 0) __builtin_amdgcn_fence(__ATOMIC_ACQUIRE, "agent");
        }
      } else if (lastx) {
        // elected: poll gCnt for all XCDs, ONE agent acquire (L1+L2 inv),
        // then publish epoch into the local L2 (plain store; L1 write-through)
        const unsigned tgt = (unsigned)nx * (unsigned)(t + 1);
        int it = 0;
        while (__hip_atomic_load(gCnt, __ATOMIC_RELAXED, __HIP_MEMORY_SCOPE_AGENT) < tgt) {
          __builtin_amdgcn_s_sleep(2);
          if ((++it & 255) == 0) __builtin_amdgcn_fence(__ATOMIC_ACQUIRE, "agent");
        }
        __builtin_amdgcn_fence(__ATOMIC_ACQUIRE, "agent");  // buffer_inv (L1+L2)
        *(volatile unsigned*)epochX = (unsigned)(t + 1);
      } else {
        // non-elected: spin on local epoch via sc0 (L1-bypass, L2-hit) loads
        const unsigned want = (unsigned)(t + 1);
        unsigned v; int it = 0; bool ok = false;
        while (true) {
          asm volatile("global_load_dword %0, %1, off sc0\n\ts_waitcnt vmcnt(0)"
                       : "=v"(v) : "v"(epochX) : "memory");
          if (v >= want) { ok = true; break; }
          __builtin_amdgcn_s_sleep(2);
          if (++it > (1 << 18)) break;     // bounded: never hang
        }
        if (ok) {
          // L2 already invalidated by elected before epoch publish;
          // drop this CU's stale L1 lines only (sc-less buffer_inv = L1 flash).
          asm volatile("buffer_inv\n\ts_waitcnt vmcnt(0)" ::: "memory");
        } else {
          // fallback: direct gCnt poll + full fence (correct, slower)
          const unsigned tgt = (unsigned)nx * (unsigned)(t + 1);
          int it2 = 0;
          while (__hip_atomic_load(gCnt, __ATOMIC_RELAXED, __HIP_MEMORY_SCOPE_AGENT) < tgt) {
            __builtin_amdgcn_s_sleep(2);
            if ((++it2 & 255) == 0) __builtin_amdgcn_fence(__ATOMIC_ACQUIRE, "agent");
          }
          __threadfence();
        }
      }
    }
    if (!elect) {
      if (tid < 64) __builtin_amdgcn_fence(__ATOMIC_ACQUIRE, "agent");
    }
    __syncthreads();
  }
}

extern "C" void kernel_launch(void* const* d_in, const int* in_sizes, int n_in,
                              void* d_out, int out_size, void* d_ws, size_t ws_size,
                              hipStream_t stream)
{
  const float* hid0  = (const float*)d_in[0];
  const float* inp0  = (const float*)d_in[1];
  const float* cell0 = (const float*)d_in[2];
  const float* W_ih  = (const float*)d_in[3];
  const float* W_hh  = (const float*)d_in[4];
  const float* b_ih  = (const float*)d_in[5];
  const float* b_hh  = (const float*)d_in[6];
  const float* W_out = (const float*)d_in[7];
  const float* b_out = (const float*)d_in[8];
  float* out = (float*)d_out;

  char* ws = (char*)d_ws;
  bf16* wp      = (bf16*)(ws + OFF_WP);
  bf16* wob     = (bf16*)(ws + OFF_WOB);
  bf16* hb0     = (bf16*)(ws + OFF_HB0);
  bf16* hb1     = (bf16*)(ws + OFF_HB1);
  float* xp     = (float*)(ws + OFF_XP);
  unsigned* bar = (unsigned*)(ws + OFF_BAR);

  prep_misc<<<512, 256, 0, stream>>>(hid0, W_out, hb0, wob, bar);
  prep_wp<<<4096, 256, 0, stream>>>(W_ih, W_hh, wp);
  prep_xp<<<512, 256, 0, stream>>>(inp0, W_ih, b_ih, b_hh, xp);

  void* args[] = { &wp, &wob, &xp, &cell0, &b_out, &hb0, &hb1, &out, &bar };
  hipError_t e = hipLaunchCooperativeKernel(lstm_main, dim3(256), dim3(256), args, 0u, stream);
  if (e != hipSuccess) {
    lstm_main<<<dim3(256), dim3(256), 0, stream>>>(wp, wob, xp, cell0, b_out,
                                                   hb0, hb1, out, bar);
  }
}

// Round 9
// 4197.065 us; speedup vs baseline: 1761.7127x; 1761.7127x over previous
//
#include <hip/hip_runtime.h>
#include <hip/hip_bf16.h>

// LSTM decoder: B=512, H=1024, NCHAR=128, T=256.
// Round 9 = round-8 with the broken acquire-spin primitive fixed.
// r8 post-mortem: epoch published via plain store + polled via sc0 asm loads
// never became visible (sc0 loads allocate/hit stale L1; sc1 is the bypass)
// -> bounded-spin timeout fired every step (28.9ms/step), fallback kept it
// correct. Fix: publish + poll the per-XCD epoch with relaxed AGENT-scope
// atomics (sc1 -> LLC), the exact primitive proven by the r6/r7 gCnt spins.
// Protocol per step:
//   release: plain h stores -> syncthreads (vmcnt drained) -> relaxed per-XCD
//     arrival add; LAST arriver per XCD: __threadfence() [wbl2 pushes all
//     XCD-mates' dirty h lines to LLC] -> RELEASE add gCnt.  (r7-proven)
//   acquire: elected (same last arriver) polls gCnt to nx*(t+1) [relaxed],
//     does ONE agent acquire fence [L1+L2 inv for this XCD], then publishes
//     epoch[myx]=t+1 via relaxed AGENT atomic store. Non-elected blocks spin
//     on epoch[myx] with relaxed AGENT atomic loads (LLC, no walks), then one
//     sc-less buffer_inv (>= this CU's vector L1). Bounded timeout -> r7-style
//     full-fence fallback (correctness net, proven in r8).
// Census degenerate -> all-flush fallback (== r6/r7 semantics).

using bf16 = __hip_bfloat16;
typedef short bf16x8 __attribute__((ext_vector_type(8)));
typedef float f32x4  __attribute__((ext_vector_type(4)));
typedef float f32x16 __attribute__((ext_vector_type(16)));

static constexpr int BATCH = 512;
static constexpr int HID   = 1024;
static constexpr int NCH   = 128;
static constexpr int TLEN  = 256;
static constexpr int NP    = 4096;   // 4*HID

// workspace byte offsets
static constexpr size_t OFF_WP  = 0;                                // bf16 [4096][1024] fused W, rows permuted
static constexpr size_t OFF_WOB = OFF_WP  + (size_t)NP * HID * 2;   // bf16 [128][1024]
static constexpr size_t OFF_HB0 = OFF_WOB + (size_t)NCH * HID * 2;  // bf16 h buffer 0
static constexpr size_t OFF_HB1 = OFF_HB0 + (size_t)BATCH * HID * 2;
static constexpr size_t OFF_XP  = OFF_HB1 + (size_t)BATCH * HID * 2; // f32 [512][4096] x_part permuted
static constexpr size_t OFF_BAR = OFF_XP  + (size_t)BATCH * NP * 4;
// bar layout (u32 index; prep_misc zeroes [0,1024)):
//   [x*32]      x<8 : per-XCD population census
//   [8*32]          : census completion counter
//   [(16+x)*32] x<8 : per-XCD per-step arrival counters (monotone)
//   [24*32]         : global step counter gCnt (monotone)
//   [800+x*16]  x<8 : per-XCD epoch words (relaxed agent atomics, LLC)

__device__ __forceinline__ float sigm(float x) { return 1.f / (1.f + __expf(-x)); }

// permuted gate-row index: row' = (j>>4)*64 + gate*16 + (j&15); decode n = gate*H + j
__device__ __forceinline__ int rowp_to_n(int rp) {
  int jg = rp >> 6, c = rp & 63;
  return (c >> 4) * HID + jg * 16 + (c & 15);
}

__global__ void prep_misc(const float* __restrict__ hid0, const float* __restrict__ wout,
                          bf16* __restrict__ hb0, bf16* __restrict__ wob,
                          unsigned* __restrict__ bar)
{
  int gid = blockIdx.x * blockDim.x + threadIdx.x;
  int stride = gridDim.x * blockDim.x;
  for (int i = gid; i < BATCH * HID; i += stride) hb0[i] = __float2bfloat16(hid0[i]);
  for (int i = gid; i < NCH * HID;  i += stride) wob[i] = __float2bfloat16(wout[i]);
  if (gid < 1024) bar[gid] = 0u;
}

__global__ void prep_wp(const float* __restrict__ W_ih, const float* __restrict__ W_hh,
                        bf16* __restrict__ wp)
{
  int gid = blockIdx.x * blockDim.x + threadIdx.x;
  int stride = gridDim.x * blockDim.x;
  for (int i = gid; i < NP * HID; i += stride) {
    int rp = i >> 10, k = i & 1023;
    int n = rowp_to_n(rp);
    float v = W_ih[(size_t)n * 1152 + 128 + k] + W_hh[(size_t)n * 1024 + k];
    wp[i] = __float2bfloat16(v);
  }
}

__global__ void prep_xp(const float* __restrict__ inp0, const float* __restrict__ W_ih,
                        const float* __restrict__ b_ih, const float* __restrict__ b_hh,
                        float* __restrict__ xp)
{
  int b = blockIdx.x;
  const float4* ip = (const float4*)(inp0 + b * NCH);
  for (int rp = threadIdx.x; rp < NP; rp += blockDim.x) {
    int n = rowp_to_n(rp);
    const float4* wr = (const float4*)(W_ih + (size_t)n * 1152);
    float acc = b_ih[n] + b_hh[n];
    #pragma unroll 8
    for (int q = 0; q < 32; ++q) {
      float4 a = ip[q], w = wr[q];
      acc += a.x * w.x + a.y * w.y + a.z * w.z + a.w * w.w;
    }
    xp[(size_t)b * NP + rp] = acc;
  }
}

__launch_bounds__(256, 1)
__global__ void lstm_main(const bf16* __restrict__ wp, const bf16* __restrict__ wob,
                          const float* __restrict__ xp, const float* __restrict__ cell0,
                          const float* __restrict__ bout,
                          bf16* __restrict__ hb0, bf16* __restrict__ hb1,
                          float* __restrict__ out, unsigned* __restrict__ bar)
{
  __shared__ bf16 wlds[64 * HID];        // 128 KB, xor-swizzled
  __shared__ float obuf[16][16][17];     // out tile x 16 buffered steps (+1 pad)
  __shared__ int s_pop[8];

  const int tid  = threadIdx.x;
  const int bx   = blockIdx.x;
  const int lane = tid & 63;
  const int wv   = tid >> 6;        // wave 0..3 (rows)
  const int bm   = bx >> 6;         // batch group 0..3 (128 rows)
  const int jg   = bx & 63;         // j group (16 h-cols -> 64 gate rows)
  const int wrow = bm * 128 + wv * 32;
  const int l31  = lane & 31;
  const int lhi  = lane >> 5;
  const bool low = (l31 < 16);
  const int jj   = lane & 15;
  const int jcol = jg * 16 + jj;

  // stage fused-W slice into LDS (swizzled: byte ^= (row&7)<<4)
  {
    const char* src = (const char*)(wp + (size_t)jg * 64 * HID);
    for (int it = tid; it < 8192; it += 256) {
      int r  = it >> 7;
      int kb = (it & 127) << 4;
      bf16x8 v = *(const bf16x8*)(src + r * 2048 + kb);
      *(bf16x8*)((char*)wlds + r * 2048 + (kb ^ ((r & 7) << 4))) = v;
    }
  }

  // x_part -> registers (constant acc init; C layout: col=lane&31, row=(q&3)+8*(q>>2)+4*lhi)
  f32x16 xpA, xpB;
  #pragma unroll
  for (int q = 0; q < 16; ++q) {
    int rr = (q & 3) + ((q >> 2) << 3) + (lhi << 2);
    const float* xr = xp + (size_t)(wrow + rr) * NP + jg * 64;
    xpA[q] = xr[l31];
    xpB[q] = xr[32 + l31];
  }

  // cell state -> registers. low half-lanes own rows {0-3,8-11}+4*lhi, high own +16.
  float creg[8];
  #pragma unroll
  for (int q = 0; q < 8; ++q) {
    int rr = (q & 3) + ((q >> 2) << 3) + (lhi << 2) + (low ? 0 : 16);
    creg[q] = cell0[(size_t)(wrow + rr) * HID + jcol];
  }

  const int omt = (bx >> 3) << 4;   // out-tile batch row base (32 tiles of 16)
  const int ont = (bx & 7) << 4;    // out-tile char col base (8 tiles of 16)
  const float bo = bout[ont + jj];

  // ---- one-time census: physical XCD id + per-XCD block population
  const int myx = __builtin_amdgcn_s_getreg(6164) & 7;  // HW_REG_XCC_ID (id=20,off=0,sz=4)
  if (tid == 0) {
    __hip_atomic_fetch_add(bar + (size_t)myx * 32, 1u, __ATOMIC_RELAXED, __HIP_MEMORY_SCOPE_AGENT);
    __threadfence();   // order pop-add before census-completion add
    __hip_atomic_fetch_add(bar + (size_t)8 * 32, 1u, __ATOMIC_RELEASE, __HIP_MEMORY_SCOPE_AGENT);
    int it = 0;
    while (__hip_atomic_load(bar + (size_t)8 * 32, __ATOMIC_RELAXED, __HIP_MEMORY_SCOPE_AGENT) < 256u) {
      __builtin_amdgcn_s_sleep(2);
      if ((++it & 255) == 0) __builtin_amdgcn_fence(__ATOMIC_ACQUIRE, "agent");
    }
  }
  __syncthreads();
  if (tid < 8)
    s_pop[tid] = (int)__hip_atomic_load(bar + (size_t)tid * 32, __ATOMIC_RELAXED, __HIP_MEMORY_SCOPE_AGENT);
  __syncthreads();
  int nx = 0, tot = 0;
  #pragma unroll
  for (int i = 0; i < 8; ++i) { nx += (s_pop[i] != 0) ? 1 : 0; tot += s_pop[i]; }
  const bool elect = (nx >= 2) && (tot == 256);   // degenerate -> all-flush (r7/r6 semantics)
  const unsigned mypop = (unsigned)s_pop[myx];
  const unsigned NF = elect ? (unsigned)nx : 256u;
  unsigned* const xcdCnt = bar + (size_t)(16 + myx) * 32;
  unsigned* const gCnt   = bar + (size_t)24 * 32;
  unsigned* const epochX = bar + (size_t)(800 + myx * 16);

  __syncthreads();

  for (int t = 0; t <= TLEN; ++t) {
    const bf16* __restrict__ hcur = (t & 1) ? hb1 : hb0;
    bf16* __restrict__ hnxt = (t & 1) ? hb0 : hb1;

    // out GEMM for step t-1 (uses h_t = hcur), wave 0 only; 16x16x1024 tile
    if (t >= 1 && wv == 0) {
      f32x4 oacc = {0.f, 0.f, 0.f, 0.f};
      const int kq = (lane >> 4) << 3;
      const bf16* ap = hcur + (size_t)(omt + jj) * HID + kq;
      const bf16* bp = wob + (size_t)(ont + jj) * HID + kq;
      #pragma unroll 8
      for (int ks = 0; ks < 32; ++ks) {
        bf16x8 av = *(const bf16x8*)(ap + ks * 32);
        bf16x8 bv = *(const bf16x8*)(bp + ks * 32);
        oacc = __builtin_amdgcn_mfma_f32_16x16x32_bf16(av, bv, oacc, 0, 0, 0);
      }
      const int slot = (t - 1) & 15;
      #pragma unroll
      for (int q = 0; q < 4; ++q)
        obuf[((lane >> 4) << 2) + q][jj][slot] = oacc[q] + bo;   // row=(l>>4)*4+q, col=jj
    }

    // flush 16 buffered output steps (coalesced 64B runs into [b][o][t] layout)
    if ((t & 15) == 0 && t >= 16) {
      __syncthreads();
      const int orow = tid >> 4, ocol = tid & 15;
      float* dst = out + ((size_t)(omt + orow) * NCH + (ont + ocol)) * TLEN + (t - 16);
      #pragma unroll
      for (int s = 0; s < 16; ++s) dst[s] = obuf[orow][ocol][s];
    }

    if (t == TLEN) break;

    // gates GEMM: [128x64] = x_part + h[128x1024] @ W'[64x1024]^T
    f32x16 accA = xpA, accB = xpB;
    {
      const bf16* ap = hcur + (size_t)(wrow + l31) * HID + (lhi << 3);
      const char* wb = (const char*)wlds;
      const int base0 = l31 * 2048;
      const int sxor  = (l31 & 7) << 4;
      const int kb4   = lhi << 4;
      #pragma unroll 8
      for (int ks = 0; ks < 64; ++ks) {
        bf16x8 av = *(const bf16x8*)(ap + ks * 16);
        const int ko = ((ks << 5) | kb4) ^ sxor;
        bf16x8 b0 = *(const bf16x8*)(wb + base0 + ko);
        bf16x8 b1 = *(const bf16x8*)(wb + base0 + 65536 + ko);
        accA = __builtin_amdgcn_mfma_f32_32x32x16_bf16(av, b0, accA, 0, 0, 0);
        accB = __builtin_amdgcn_mfma_f32_32x32x16_bf16(av, b1, accB, 0, 0, 0);
      }
    }

    // LSTM cell update. accA cols: i (l31<16) / f (l31>=16); accB: g / o.
    float s0[16], s1[16], u0[16], u1[16];
    #pragma unroll
    for (int q = 0; q < 16; ++q) {
      s0[q] = sigm(accA[q]);                       // sig(i) on low, sig(f) on high
      float a1 = accB[q];
      float sg = sigm(low ? 2.f * a1 : a1);
      s1[q] = low ? 2.f * sg - 1.f : sg;           // tanh(g) on low, sig(o) on high
    }
    #pragma unroll
    for (int q = 0; q < 16; ++q) {
      u0[q] = __shfl_xor(s0[q], 16);
      u1[q] = __shfl_xor(s1[q], 16);
    }
    #pragma unroll
    for (int q = 0; q < 8; ++q) {
      float fg  = low ? u0[q]         : s0[q + 8];
      float ig  = low ? s0[q] * s1[q] : u0[q + 8] * u1[q + 8];
      float og  = low ? u1[q]         : s1[q + 8];
      float cn  = fg * creg[q] + ig;
      creg[q] = cn;
      float hv = og * (2.f * sigm(2.f * cn) - 1.f);
      int rr = (q & 3) + ((q >> 2) << 3) + (lhi << 2) + (low ? 0 : 16);
      hnxt[(size_t)(wrow + rr) * HID + jcol] = __float2bfloat16(hv);
    }

    // ---- grid barrier: elected release (r7) + elected acquire (fixed spin) ----
    // syncthreads drains vmcnt -> all 4 waves' h stores are in this XCD's L2.
    __syncthreads();
    if (tid == 0) {
      unsigned old = __hip_atomic_fetch_add(xcdCnt, 1u, __ATOMIC_RELAXED, __HIP_MEMORY_SCOPE_AGENT);
      const bool lastx = !elect || (old == mypop * (unsigned)(t + 1) - 1u);
      if (lastx) {
        // last arriver on this XCD: all XCD-mates' stores are in this L2.
        __threadfence();   // buffer_wbl2: push them to the LLC (r7-proven)
        __hip_atomic_fetch_add(gCnt, 1u, __ATOMIC_RELEASE, __HIP_MEMORY_SCOPE_AGENT);
      }
      if (!elect) {
        // fallback: r7 shape -- every block polls gCnt
        const unsigned tgt = NF * (unsigned)(t + 1);
        int it = 0;
        while (__hip_atomic_load(gCnt, __ATOMIC_RELAXED, __HIP_MEMORY_SCOPE_AGENT) < tgt) {
          __builtin_amdgcn_s_sleep(2);
          if ((++it & 255) == 0) __builtin_amdgcn_fence(__ATOMIC_ACQUIRE, "agent");
        }
      } else if (lastx) {
        // elected: poll gCnt for all XCDs, ONE agent acquire (L1+L2 inv),
        // then publish epoch via relaxed AGENT atomic (sc1 -> LLC; the
        // proven-visible primitive, unlike r8's plain store + sc0 spin).
        const unsigned tgt = (unsigned)nx * (unsigned)(t + 1);
        int it = 0;
        while (__hip_atomic_load(gCnt, __ATOMIC_RELAXED, __HIP_MEMORY_SCOPE_AGENT) < tgt) {
          __builtin_amdgcn_s_sleep(2);
          if ((++it & 255) == 0) __builtin_amdgcn_fence(__ATOMIC_ACQUIRE, "agent");
        }
        __builtin_amdgcn_fence(__ATOMIC_ACQUIRE, "agent");  // buffer_inv (L1+L2)
        __hip_atomic_store(epochX, (unsigned)(t + 1), __ATOMIC_RELAXED, __HIP_MEMORY_SCOPE_AGENT);
      } else {
        // non-elected: spin on own-XCD epoch with relaxed AGENT loads (LLC).
        const unsigned want = (unsigned)(t + 1);
        int it = 0; bool ok = false;
        while (true) {
          if (__hip_atomic_load(epochX, __ATOMIC_RELAXED, __HIP_MEMORY_SCOPE_AGENT) >= want) { ok = true; break; }
          __builtin_amdgcn_s_sleep(2);
          if (++it > (1 << 18)) break;     // bounded: never hang
        }
        if (ok) {
          // L2 already invalidated by elected before epoch publish; drop this
          // CU's stale vector-L1 lines (sc-less buffer_inv; compiled in r8).
          asm volatile("buffer_inv" ::: "memory");
        } else {
          // fallback: direct gCnt poll + full fence (correct; carried r8)
          const unsigned tgt = (unsigned)nx * (unsigned)(t + 1);
          int it2 = 0;
          while (__hip_atomic_load(gCnt, __ATOMIC_RELAXED, __HIP_MEMORY_SCOPE_AGENT) < tgt) {
            __builtin_amdgcn_s_sleep(2);
            if ((++it2 & 255) == 0) __builtin_amdgcn_fence(__ATOMIC_ACQUIRE, "agent");
          }
          __threadfence();
        }
      }
    }
    if (!elect) {
      if (tid < 64) __builtin_amdgcn_fence(__ATOMIC_ACQUIRE, "agent");
    }
    __syncthreads();
  }
}

extern "C" void kernel_launch(void* const* d_in, const int* in_sizes, int n_in,
                              void* d_out, int out_size, void* d_ws, size_t ws_size,
                              hipStream_t stream)
{
  const float* hid0  = (const float*)d_in[0];
  const float* inp0  = (const float*)d_in[1];
  const float* cell0 = (const float*)d_in[2];
  const float* W_ih  = (const float*)d_in[3];
  const float* W_hh  = (const float*)d_in[4];
  const float* b_ih  = (const float*)d_in[5];
  const float* b_hh  = (const float*)d_in[6];
  const float* W_out = (const float*)d_in[7];
  const float* b_out = (const float*)d_in[8];
  float* out = (float*)d_out;

  char* ws = (char*)d_ws;
  bf16* wp      = (bf16*)(ws + OFF_WP);
  bf16* wob     = (bf16*)(ws + OFF_WOB);
  bf16* hb0     = (bf16*)(ws + OFF_HB0);
  bf16* hb1     = (bf16*)(ws + OFF_HB1);
  float* xp     = (float*)(ws + OFF_XP);
  unsigned* bar = (unsigned*)(ws + OFF_BAR);

  prep_misc<<<512, 256, 0, stream>>>(hid0, W_out, hb0, wob, bar);
  prep_wp<<<4096, 256, 0, stream>>>(W_ih, W_hh, wp);
  prep_xp<<<512, 256, 0, stream>>>(inp0, W_ih, b_ih, b_hh, xp);

  void* args[] = { &wp, &wob, &xp, &cell0, &b_out, &hb0, &hb1, &out, &bar };
  hipError_t e = hipLaunchCooperativeKernel(lstm_main, dim3(256), dim3(256), args, 0u, stream);
  if (e != hipSuccess) {
    lstm_main<<<dim3(256), dim3(256), 0, stream>>>(wp, wob, xp, cell0, b_out,
                                                   hb0, hb1, out, bar);
  }
}

// Round 10
// 3953.056 us; speedup vs baseline: 1870.4572x; 1.0617x over previous
//
#include <hip/hip_runtime.h>
#include <hip/hip_bf16.h>

// LSTM decoder: B=512, H=1024, NCHAR=128, T=256.
// Round 10 = round-9 (PASSED, 4197us) + three contained fixes, barrier
// protocol semantics untouched:
//  1. out GEMM split-K across all 4 waves (was wave-0-only straggler):
//     partials -> LDS opart[4][16][16] -> 256-thread reduce into obuf.
//  2. W-LDS swizzle widened 3->4 row bits ((row&15)<<4): b128 reads go
//     4-way -> 2-way bank aliasing (2-way is free, m136).
//  3. spin s_sleep(2)->s_sleep(1); gates K-loop unroll 8->16 (VGPRs free,
//     occupancy is LDS-capped at 1 block/CU).
// Barrier (r7/r9-proven): release = plain h stores -> syncthreads ->
// relaxed per-XCD arrival; LAST arriver per XCD does __threadfence()
// [wbl2 -> LLC] -> RELEASE add gCnt. acquire = elected polls gCnt, ONE
// agent acquire fence (L2 inv), publishes per-XCD epoch (relaxed agent
// atomic, sc1/LLC); others spin on epoch relaxed, then sc-less buffer_inv
// (L1). Bounded timeout -> full-fence fallback. Census degenerate ->
// all-flush fallback.

using bf16 = __hip_bfloat16;
typedef short bf16x8 __attribute__((ext_vector_type(8)));
typedef float f32x4  __attribute__((ext_vector_type(4)));
typedef float f32x16 __attribute__((ext_vector_type(16)));

static constexpr int BATCH = 512;
static constexpr int HID   = 1024;
static constexpr int NCH   = 128;
static constexpr int TLEN  = 256;
static constexpr int NP    = 4096;   // 4*HID

// workspace byte offsets
static constexpr size_t OFF_WP  = 0;                                // bf16 [4096][1024] fused W, rows permuted
static constexpr size_t OFF_WOB = OFF_WP  + (size_t)NP * HID * 2;   // bf16 [128][1024]
static constexpr size_t OFF_HB0 = OFF_WOB + (size_t)NCH * HID * 2;  // bf16 h buffer 0
static constexpr size_t OFF_HB1 = OFF_HB0 + (size_t)BATCH * HID * 2;
static constexpr size_t OFF_XP  = OFF_HB1 + (size_t)BATCH * HID * 2; // f32 [512][4096] x_part permuted
static constexpr size_t OFF_BAR = OFF_XP  + (size_t)BATCH * NP * 4;
// bar layout (u32 index; prep_misc zeroes [0,1024)):
//   [x*32]      x<8 : per-XCD population census
//   [8*32]          : census completion counter
//   [(16+x)*32] x<8 : per-XCD per-step arrival counters (monotone)
//   [24*32]         : global step counter gCnt (monotone)
//   [800+x*16]  x<8 : per-XCD epoch words (relaxed agent atomics, LLC)

__device__ __forceinline__ float sigm(float x) { return 1.f / (1.f + __expf(-x)); }

// permuted gate-row index: row' = (j>>4)*64 + gate*16 + (j&15); decode n = gate*H + j
__device__ __forceinline__ int rowp_to_n(int rp) {
  int jg = rp >> 6, c = rp & 63;
  return (c >> 4) * HID + jg * 16 + (c & 15);
}

__global__ void prep_misc(const float* __restrict__ hid0, const float* __restrict__ wout,
                          bf16* __restrict__ hb0, bf16* __restrict__ wob,
                          unsigned* __restrict__ bar)
{
  int gid = blockIdx.x * blockDim.x + threadIdx.x;
  int stride = gridDim.x * blockDim.x;
  for (int i = gid; i < BATCH * HID; i += stride) hb0[i] = __float2bfloat16(hid0[i]);
  for (int i = gid; i < NCH * HID;  i += stride) wob[i] = __float2bfloat16(wout[i]);
  if (gid < 1024) bar[gid] = 0u;
}

__global__ void prep_wp(const float* __restrict__ W_ih, const float* __restrict__ W_hh,
                        bf16* __restrict__ wp)
{
  int gid = blockIdx.x * blockDim.x + threadIdx.x;
  int stride = gridDim.x * blockDim.x;
  for (int i = gid; i < NP * HID; i += stride) {
    int rp = i >> 10, k = i & 1023;
    int n = rowp_to_n(rp);
    float v = W_ih[(size_t)n * 1152 + 128 + k] + W_hh[(size_t)n * 1024 + k];
    wp[i] = __float2bfloat16(v);
  }
}

__global__ void prep_xp(const float* __restrict__ inp0, const float* __restrict__ W_ih,
                        const float* __restrict__ b_ih, const float* __restrict__ b_hh,
                        float* __restrict__ xp)
{
  int b = blockIdx.x;
  const float4* ip = (const float4*)(inp0 + b * NCH);
  for (int rp = threadIdx.x; rp < NP; rp += blockDim.x) {
    int n = rowp_to_n(rp);
    const float4* wr = (const float4*)(W_ih + (size_t)n * 1152);
    float acc = b_ih[n] + b_hh[n];
    #pragma unroll 8
    for (int q = 0; q < 32; ++q) {
      float4 a = ip[q], w = wr[q];
      acc += a.x * w.x + a.y * w.y + a.z * w.z + a.w * w.w;
    }
    xp[(size_t)b * NP + rp] = acc;
  }
}

__launch_bounds__(256, 1)
__global__ void lstm_main(const bf16* __restrict__ wp, const bf16* __restrict__ wob,
                          const float* __restrict__ xp, const float* __restrict__ cell0,
                          const float* __restrict__ bout,
                          bf16* __restrict__ hb0, bf16* __restrict__ hb1,
                          float* __restrict__ out, unsigned* __restrict__ bar)
{
  __shared__ bf16 wlds[64 * HID];        // 128 KB, xor-swizzled (4 row bits)
  __shared__ float obuf[16][16][17];     // out tile x 16 buffered steps (+1 pad)
  __shared__ float opart[4][16][16];     // per-wave out-GEMM partials (split-K)
  __shared__ int s_pop[8];

  const int tid  = threadIdx.x;
  const int bx   = blockIdx.x;
  const int lane = tid & 63;
  const int wv   = tid >> 6;        // wave 0..3 (rows)
  const int bm   = bx >> 6;         // batch group 0..3 (128 rows)
  const int jg   = bx & 63;         // j group (16 h-cols -> 64 gate rows)
  const int wrow = bm * 128 + wv * 32;
  const int l31  = lane & 31;
  const int lhi  = lane >> 5;
  const bool low = (l31 < 16);
  const int jj   = lane & 15;
  const int jcol = jg * 16 + jj;

  // stage fused-W slice into LDS (swizzled: byte ^= (row&15)<<4)
  {
    const char* src = (const char*)(wp + (size_t)jg * 64 * HID);
    for (int it = tid; it < 8192; it += 256) {
      int r  = it >> 7;
      int kb = (it & 127) << 4;
      bf16x8 v = *(const bf16x8*)(src + r * 2048 + kb);
      *(bf16x8*)((char*)wlds + r * 2048 + (kb ^ ((r & 15) << 4))) = v;
    }
  }

  // x_part -> registers (constant acc init; C layout: col=lane&31, row=(q&3)+8*(q>>2)+4*lhi)
  f32x16 xpA, xpB;
  #pragma unroll
  for (int q = 0; q < 16; ++q) {
    int rr = (q & 3) + ((q >> 2) << 3) + (lhi << 2);
    const float* xr = xp + (size_t)(wrow + rr) * NP + jg * 64;
    xpA[q] = xr[l31];
    xpB[q] = xr[32 + l31];
  }

  // cell state -> registers. low half-lanes own rows {0-3,8-11}+4*lhi, high own +16.
  float creg[8];
  #pragma unroll
  for (int q = 0; q < 8; ++q) {
    int rr = (q & 3) + ((q >> 2) << 3) + (lhi << 2) + (low ? 0 : 16);
    creg[q] = cell0[(size_t)(wrow + rr) * HID + jcol];
  }

  const int omt = (bx >> 3) << 4;   // out-tile batch row base (32 tiles of 16)
  const int ont = (bx & 7) << 4;    // out-tile char col base (8 tiles of 16)
  const float bo = bout[ont + jj];  // jj == tid&15, reused by the reduce

  // ---- one-time census: physical XCD id + per-XCD block population
  const int myx = __builtin_amdgcn_s_getreg(6164) & 7;  // HW_REG_XCC_ID (id=20,off=0,sz=4)
  if (tid == 0) {
    __hip_atomic_fetch_add(bar + (size_t)myx * 32, 1u, __ATOMIC_RELAXED, __HIP_MEMORY_SCOPE_AGENT);
    __threadfence();   // order pop-add before census-completion add
    __hip_atomic_fetch_add(bar + (size_t)8 * 32, 1u, __ATOMIC_RELEASE, __HIP_MEMORY_SCOPE_AGENT);
    int it = 0;
    while (__hip_atomic_load(bar + (size_t)8 * 32, __ATOMIC_RELAXED, __HIP_MEMORY_SCOPE_AGENT) < 256u) {
      __builtin_amdgcn_s_sleep(1);
      if ((++it & 255) == 0) __builtin_amdgcn_fence(__ATOMIC_ACQUIRE, "agent");
    }
  }
  __syncthreads();
  if (tid < 8)
    s_pop[tid] = (int)__hip_atomic_load(bar + (size_t)tid * 32, __ATOMIC_RELAXED, __HIP_MEMORY_SCOPE_AGENT);
  __syncthreads();
  int nx = 0, tot = 0;
  #pragma unroll
  for (int i = 0; i < 8; ++i) { nx += (s_pop[i] != 0) ? 1 : 0; tot += s_pop[i]; }
  const bool elect = (nx >= 2) && (tot == 256);   // degenerate -> all-flush (r7/r6 semantics)
  const unsigned mypop = (unsigned)s_pop[myx];
  const unsigned NF = elect ? (unsigned)nx : 256u;
  unsigned* const xcdCnt = bar + (size_t)(16 + myx) * 32;
  unsigned* const gCnt   = bar + (size_t)24 * 32;
  unsigned* const epochX = bar + (size_t)(800 + myx * 16);

  __syncthreads();

  for (int t = 0; t <= TLEN; ++t) {
    const bf16* __restrict__ hcur = (t & 1) ? hb1 : hb0;
    bf16* __restrict__ hnxt = (t & 1) ? hb0 : hb1;

    // ---- out GEMM for step t-1 (uses h_t = hcur): split-K across 4 waves.
    //      wave wv covers K in [wv*256, wv*256+256); partials to opart.
    if (t >= 1) {
      f32x4 oacc = {0.f, 0.f, 0.f, 0.f};
      const int kq = (lane >> 4) << 3;
      const bf16* ap = hcur + (size_t)(omt + jj) * HID + kq;
      const bf16* bp = wob + (size_t)(ont + jj) * HID + kq;
      #pragma unroll
      for (int ks = wv * 8; ks < wv * 8 + 8; ++ks) {
        bf16x8 av = *(const bf16x8*)(ap + ks * 32);
        bf16x8 bv = *(const bf16x8*)(bp + ks * 32);
        oacc = __builtin_amdgcn_mfma_f32_16x16x32_bf16(av, bv, oacc, 0, 0, 0);
      }
      #pragma unroll
      for (int q = 0; q < 4; ++q)
        opart[wv][((lane >> 4) << 2) + q][jj] = oacc[q];   // row=(l>>4)*4+q, col=jj
    }
    __syncthreads();
    if (t >= 1) {
      const int orow = tid >> 4, ocol = tid & 15;
      float s = opart[0][orow][ocol] + opart[1][orow][ocol]
              + opart[2][orow][ocol] + opart[3][orow][ocol];
      obuf[orow][ocol][(t - 1) & 15] = s + bo;
    }

    // flush 16 buffered output steps (coalesced 64B runs into [b][o][t] layout)
    if ((t & 15) == 0 && t >= 16) {
      __syncthreads();
      const int orow = tid >> 4, ocol = tid & 15;
      float* dst = out + ((size_t)(omt + orow) * NCH + (ont + ocol)) * TLEN + (t - 16);
      #pragma unroll
      for (int s = 0; s < 16; ++s) dst[s] = obuf[orow][ocol][s];
    }

    if (t == TLEN) break;

    // gates GEMM: [128x64] = x_part + h[128x1024] @ W'[64x1024]^T
    f32x16 accA = xpA, accB = xpB;
    {
      const bf16* ap = hcur + (size_t)(wrow + l31) * HID + (lhi << 3);
      const char* wb = (const char*)wlds;
      const int base0 = l31 * 2048;
      const int sxor  = (l31 & 15) << 4;   // matches 4-bit staging swizzle
      const int kb4   = lhi << 4;
      #pragma unroll 16
      for (int ks = 0; ks < 64; ++ks) {
        bf16x8 av = *(const bf16x8*)(ap + ks * 16);
        const int ko = ((ks << 5) | kb4) ^ sxor;
        bf16x8 b0 = *(const bf16x8*)(wb + base0 + ko);
        bf16x8 b1 = *(const bf16x8*)(wb + base0 + 65536 + ko);
        accA = __builtin_amdgcn_mfma_f32_32x32x16_bf16(av, b0, accA, 0, 0, 0);
        accB = __builtin_amdgcn_mfma_f32_32x32x16_bf16(av, b1, accB, 0, 0, 0);
      }
    }

    // LSTM cell update. accA cols: i (l31<16) / f (l31>=16); accB: g / o.
    float s0[16], s1[16], u0[16], u1[16];
    #pragma unroll
    for (int q = 0; q < 16; ++q) {
      s0[q] = sigm(accA[q]);                       // sig(i) on low, sig(f) on high
      float a1 = accB[q];
      float sg = sigm(low ? 2.f * a1 : a1);
      s1[q] = low ? 2.f * sg - 1.f : sg;           // tanh(g) on low, sig(o) on high
    }
    #pragma unroll
    for (int q = 0; q < 16; ++q) {
      u0[q] = __shfl_xor(s0[q], 16);
      u1[q] = __shfl_xor(s1[q], 16);
    }
    #pragma unroll
    for (int q = 0; q < 8; ++q) {
      float fg  = low ? u0[q]         : s0[q + 8];
      float ig  = low ? s0[q] * s1[q] : u0[q + 8] * u1[q + 8];
      float og  = low ? u1[q]         : s1[q + 8];
      float cn  = fg * creg[q] + ig;
      creg[q] = cn;
      float hv = og * (2.f * sigm(2.f * cn) - 1.f);
      int rr = (q & 3) + ((q >> 2) << 3) + (lhi << 2) + (low ? 0 : 16);
      hnxt[(size_t)(wrow + rr) * HID + jcol] = __float2bfloat16(hv);
    }

    // ---- grid barrier: elected release + elected acquire (r9-proven) ----
    __syncthreads();
    if (tid == 0) {
      unsigned old = __hip_atomic_fetch_add(xcdCnt, 1u, __ATOMIC_RELAXED, __HIP_MEMORY_SCOPE_AGENT);
      const bool lastx = !elect || (old == mypop * (unsigned)(t + 1) - 1u);
      if (lastx) {
        // last arriver on this XCD: all XCD-mates' stores are in this L2.
        __threadfence();   // buffer_wbl2: push them to the LLC
        __hip_atomic_fetch_add(gCnt, 1u, __ATOMIC_RELEASE, __HIP_MEMORY_SCOPE_AGENT);
      }
      if (!elect) {
        const unsigned tgt = NF * (unsigned)(t + 1);
        int it = 0;
        while (__hip_atomic_load(gCnt, __ATOMIC_RELAXED, __HIP_MEMORY_SCOPE_AGENT) < tgt) {
          __builtin_amdgcn_s_sleep(1);
          if ((++it & 255) == 0) __builtin_amdgcn_fence(__ATOMIC_ACQUIRE, "agent");
        }
      } else if (lastx) {
        // elected: poll gCnt for all XCDs, ONE agent acquire (L2 inv),
        // then publish epoch via relaxed AGENT atomic (sc1 -> LLC).
        const unsigned tgt = (unsigned)nx * (unsigned)(t + 1);
        int it = 0;
        while (__hip_atomic_load(gCnt, __ATOMIC_RELAXED, __HIP_MEMORY_SCOPE_AGENT) < tgt) {
          __builtin_amdgcn_s_sleep(1);
          if ((++it & 255) == 0) __builtin_amdgcn_fence(__ATOMIC_ACQUIRE, "agent");
        }
        __builtin_amdgcn_fence(__ATOMIC_ACQUIRE, "agent");  // buffer_inv (L1+L2)
        __hip_atomic_store(epochX, (unsigned)(t + 1), __ATOMIC_RELAXED, __HIP_MEMORY_SCOPE_AGENT);
      } else {
        // non-elected: spin on own-XCD epoch with relaxed AGENT loads (LLC).
        const unsigned want = (unsigned)(t + 1);
        int it = 0; bool ok = false;
        while (true) {
          if (__hip_atomic_load(epochX, __ATOMIC_RELAXED, __HIP_MEMORY_SCOPE_AGENT) >= want) { ok = true; break; }
          __builtin_amdgcn_s_sleep(1);
          if (++it > (1 << 18)) break;     // bounded: never hang
        }
        if (ok) {
          // L2 already inv'd by elected pre-publish; drop this CU's stale L1.
          asm volatile("buffer_inv" ::: "memory");
        } else {
          // fallback: direct gCnt poll + full fence (correct; carried r8)
          const unsigned tgt = (unsigned)nx * (unsigned)(t + 1);
          int it2 = 0;
          while (__hip_atomic_load(gCnt, __ATOMIC_RELAXED, __HIP_MEMORY_SCOPE_AGENT) < tgt) {
            __builtin_amdgcn_s_sleep(1);
            if ((++it2 & 255) == 0) __builtin_amdgcn_fence(__ATOMIC_ACQUIRE, "agent");
          }
          __threadfence();
        }
      }
    }
    if (!elect) {
      if (tid < 64) __builtin_amdgcn_fence(__ATOMIC_ACQUIRE, "agent");
    }
    __syncthreads();
  }
}

extern "C" void kernel_launch(void* const* d_in, const int* in_sizes, int n_in,
                              void* d_out, int out_size, void* d_ws, size_t ws_size,
                              hipStream_t stream)
{
  const float* hid0  = (const float*)d_in[0];
  const float* inp0  = (const float*)d_in[1];
  const float* cell0 = (const float*)d_in[2];
  const float* W_ih  = (const float*)d_in[3];
  const float* W_hh  = (const float*)d_in[4];
  const float* b_ih  = (const float*)d_in[5];
  const float* b_hh  = (const float*)d_in[6];
  const float* W_out = (const float*)d_in[7];
  const float* b_out = (const float*)d_in[8];
  float* out = (float*)d_out;

  char* ws = (char*)d_ws;
  bf16* wp      = (bf16*)(ws + OFF_WP);
  bf16* wob     = (bf16*)(ws + OFF_WOB);
  bf16* hb0     = (bf16*)(ws + OFF_HB0);
  bf16* hb1     = (bf16*)(ws + OFF_HB1);
  float* xp     = (float*)(ws + OFF_XP);
  unsigned* bar = (unsigned*)(ws + OFF_BAR);

  prep_misc<<<512, 256, 0, stream>>>(hid0, W_out, hb0, wob, bar);
  prep_wp<<<4096, 256, 0, stream>>>(W_ih, W_hh, wp);
  prep_xp<<<512, 256, 0, stream>>>(inp0, W_ih, b_ih, b_hh, xp);

  void* args[] = { &wp, &wob, &xp, &cell0, &b_out, &hb0, &hb1, &out, &bar };
  hipError_t e = hipLaunchCooperativeKernel(lstm_main, dim3(256), dim3(256), args, 0u, stream);
  if (e != hipSuccess) {
    lstm_main<<<dim3(256), dim3(256), 0, stream>>>(wp, wob, xp, cell0, b_out,
                                                   hb0, hb1, out, bar);
  }
}

// Round 11
// 3765.389 us; speedup vs baseline: 1963.6810x; 1.0498x over previous
//
#include <hip/hip_runtime.h>
#include <hip/hip_bf16.h>

// LSTM decoder: B=512, H=1024, NCHAR=128, T=256.
// Round 11 = round-10 (PASSED, 3953us) + ONE change-cluster: zero-wbl2
// release. h stores become packed-u32 agent-scope RELAXED atomic stores
// (sc1 -> write-through to LLC; no dirty L2 h lines ever). Release is then
// pure counters: per-wave vmcnt(0) + syncthreads + relaxed per-XCD arrival
// add; last arriver adds gCnt RELAXED (no threadfence, no wbl2 -- its add
// issues after its arrival RMW returned, hence after all mates' stores are
// LLC-visible). Acquire unchanged from r10 (elected: poll gCnt -> ONE agent
// acquire fence (inv, cheap per r9) -> publish per-XCD epoch; others spin
// relaxed on epoch then L1 buffer_inv). Fallbacks keep conservative fences.
// Model-check prediction: FETCH_SIZE drops (h stops bouncing through HBM).

using bf16 = __hip_bfloat16;
typedef short bf16x8 __attribute__((ext_vector_type(8)));
typedef float f32x4  __attribute__((ext_vector_type(4)));
typedef float f32x16 __attribute__((ext_vector_type(16)));

static constexpr int BATCH = 512;
static constexpr int HID   = 1024;
static constexpr int NCH   = 128;
static constexpr int TLEN  = 256;
static constexpr int NP    = 4096;   // 4*HID

// workspace byte offsets
static constexpr size_t OFF_WP  = 0;                                // bf16 [4096][1024] fused W, rows permuted
static constexpr size_t OFF_WOB = OFF_WP  + (size_t)NP * HID * 2;   // bf16 [128][1024]
static constexpr size_t OFF_HB0 = OFF_WOB + (size_t)NCH * HID * 2;  // bf16 h buffer 0
static constexpr size_t OFF_HB1 = OFF_HB0 + (size_t)BATCH * HID * 2;
static constexpr size_t OFF_XP  = OFF_HB1 + (size_t)BATCH * HID * 2; // f32 [512][4096] x_part permuted
static constexpr size_t OFF_BAR = OFF_XP  + (size_t)BATCH * NP * 4;
// bar layout (u32 index; prep_misc zeroes [0,1024)):
//   [x*32]      x<8 : per-XCD population census
//   [8*32]          : census completion counter
//   [(16+x)*32] x<8 : per-XCD per-step arrival counters (monotone)
//   [24*32]         : global step counter gCnt (monotone)
//   [800+x*16]  x<8 : per-XCD epoch words (relaxed agent atomics, LLC)

__device__ __forceinline__ float sigm(float x) { return 1.f / (1.f + __expf(-x)); }

__device__ __forceinline__ unsigned short f2bf(float x) {
  unsigned u = __float_as_uint(x);
  return (unsigned short)((u + 0x7FFFu + ((u >> 16) & 1u)) >> 16);
}

// permuted gate-row index: row' = (j>>4)*64 + gate*16 + (j&15); decode n = gate*H + j
__device__ __forceinline__ int rowp_to_n(int rp) {
  int jg = rp >> 6, c = rp & 63;
  return (c >> 4) * HID + jg * 16 + (c & 15);
}

__global__ void prep_misc(const float* __restrict__ hid0, const float* __restrict__ wout,
                          bf16* __restrict__ hb0, bf16* __restrict__ wob,
                          unsigned* __restrict__ bar)
{
  int gid = blockIdx.x * blockDim.x + threadIdx.x;
  int stride = gridDim.x * blockDim.x;
  for (int i = gid; i < BATCH * HID; i += stride) hb0[i] = __float2bfloat16(hid0[i]);
  for (int i = gid; i < NCH * HID;  i += stride) wob[i] = __float2bfloat16(wout[i]);
  if (gid < 1024) bar[gid] = 0u;
}

__global__ void prep_wp(const float* __restrict__ W_ih, const float* __restrict__ W_hh,
                        bf16* __restrict__ wp)
{
  int gid = blockIdx.x * blockDim.x + threadIdx.x;
  int stride = gridDim.x * blockDim.x;
  for (int i = gid; i < NP * HID; i += stride) {
    int rp = i >> 10, k = i & 1023;
    int n = rowp_to_n(rp);
    float v = W_ih[(size_t)n * 1152 + 128 + k] + W_hh[(size_t)n * 1024 + k];
    wp[i] = __float2bfloat16(v);
  }
}

__global__ void prep_xp(const float* __restrict__ inp0, const float* __restrict__ W_ih,
                        const float* __restrict__ b_ih, const float* __restrict__ b_hh,
                        float* __restrict__ xp)
{
  int b = blockIdx.x;
  const float4* ip = (const float4*)(inp0 + b * NCH);
  for (int rp = threadIdx.x; rp < NP; rp += blockDim.x) {
    int n = rowp_to_n(rp);
    const float4* wr = (const float4*)(W_ih + (size_t)n * 1152);
    float acc = b_ih[n] + b_hh[n];
    #pragma unroll 8
    for (int q = 0; q < 32; ++q) {
      float4 a = ip[q], w = wr[q];
      acc += a.x * w.x + a.y * w.y + a.z * w.z + a.w * w.w;
    }
    xp[(size_t)b * NP + rp] = acc;
  }
}

__launch_bounds__(256, 1)
__global__ void lstm_main(const bf16* __restrict__ wp, const bf16* __restrict__ wob,
                          const float* __restrict__ xp, const float* __restrict__ cell0,
                          const float* __restrict__ bout,
                          bf16* __restrict__ hb0, bf16* __restrict__ hb1,
                          float* __restrict__ out, unsigned* __restrict__ bar)
{
  __shared__ bf16 wlds[64 * HID];        // 128 KB, xor-swizzled (4 row bits)
  __shared__ float obuf[16][16][17];     // out tile x 16 buffered steps (+1 pad)
  __shared__ float opart[4][16][16];     // per-wave out-GEMM partials (split-K)
  __shared__ int s_pop[8];

  const int tid  = threadIdx.x;
  const int bx   = blockIdx.x;
  const int lane = tid & 63;
  const int wv   = tid >> 6;        // wave 0..3 (rows)
  const int bm   = bx >> 6;         // batch group 0..3 (128 rows)
  const int jg   = bx & 63;         // j group (16 h-cols -> 64 gate rows)
  const int wrow = bm * 128 + wv * 32;
  const int l31  = lane & 31;
  const int lhi  = lane >> 5;
  const bool low = (l31 < 16);
  const int jj   = lane & 15;
  const int jcol = jg * 16 + jj;

  // stage fused-W slice into LDS (swizzled: byte ^= (row&15)<<4)
  {
    const char* src = (const char*)(wp + (size_t)jg * 64 * HID);
    for (int it = tid; it < 8192; it += 256) {
      int r  = it >> 7;
      int kb = (it & 127) << 4;
      bf16x8 v = *(const bf16x8*)(src + r * 2048 + kb);
      *(bf16x8*)((char*)wlds + r * 2048 + (kb ^ ((r & 15) << 4))) = v;
    }
  }

  // x_part -> registers (constant acc init; C layout: col=lane&31, row=(q&3)+8*(q>>2)+4*lhi)
  f32x16 xpA, xpB;
  #pragma unroll
  for (int q = 0; q < 16; ++q) {
    int rr = (q & 3) + ((q >> 2) << 3) + (lhi << 2);
    const float* xr = xp + (size_t)(wrow + rr) * NP + jg * 64;
    xpA[q] = xr[l31];
    xpB[q] = xr[32 + l31];
  }

  // cell state -> registers. low half-lanes own rows {0-3,8-11}+4*lhi, high own +16.
  float creg[8];
  #pragma unroll
  for (int q = 0; q < 8; ++q) {
    int rr = (q & 3) + ((q >> 2) << 3) + (lhi << 2) + (low ? 0 : 16);
    creg[q] = cell0[(size_t)(wrow + rr) * HID + jcol];
  }

  const int omt = (bx >> 3) << 4;   // out-tile batch row base (32 tiles of 16)
  const int ont = (bx & 7) << 4;    // out-tile char col base (8 tiles of 16)
  const float bo = bout[ont + jj];  // jj == tid&15, reused by the reduce

  // ---- one-time census: physical XCD id + per-XCD block population
  const int myx = __builtin_amdgcn_s_getreg(6164) & 7;  // HW_REG_XCC_ID (id=20,off=0,sz=4)
  if (tid == 0) {
    __hip_atomic_fetch_add(bar + (size_t)myx * 32, 1u, __ATOMIC_RELAXED, __HIP_MEMORY_SCOPE_AGENT);
    __threadfence();   // order pop-add before census-completion add
    __hip_atomic_fetch_add(bar + (size_t)8 * 32, 1u, __ATOMIC_RELEASE, __HIP_MEMORY_SCOPE_AGENT);
    int it = 0;
    while (__hip_atomic_load(bar + (size_t)8 * 32, __ATOMIC_RELAXED, __HIP_MEMORY_SCOPE_AGENT) < 256u) {
      __builtin_amdgcn_s_sleep(1);
      if ((++it & 255) == 0) __builtin_amdgcn_fence(__ATOMIC_ACQUIRE, "agent");
    }
  }
  __syncthreads();
  if (tid < 8)
    s_pop[tid] = (int)__hip_atomic_load(bar + (size_t)tid * 32, __ATOMIC_RELAXED, __HIP_MEMORY_SCOPE_AGENT);
  __syncthreads();
  int nx = 0, tot = 0;
  #pragma unroll
  for (int i = 0; i < 8; ++i) { nx += (s_pop[i] != 0) ? 1 : 0; tot += s_pop[i]; }
  const bool elect = (nx >= 2) && (tot == 256);   // degenerate -> all-flush (r7/r6 semantics)
  const unsigned mypop = (unsigned)s_pop[myx];
  const unsigned NF = elect ? (unsigned)nx : 256u;
  unsigned* const xcdCnt = bar + (size_t)(16 + myx) * 32;
  unsigned* const gCnt   = bar + (size_t)24 * 32;
  unsigned* const epochX = bar + (size_t)(800 + myx * 16);

  __syncthreads();

  for (int t = 0; t <= TLEN; ++t) {
    const bf16* __restrict__ hcur = (t & 1) ? hb1 : hb0;
    bf16* __restrict__ hnxt = (t & 1) ? hb0 : hb1;

    // ---- out GEMM for step t-1 (uses h_t = hcur): split-K across 4 waves.
    if (t >= 1) {
      f32x4 oacc = {0.f, 0.f, 0.f, 0.f};
      const int kq = (lane >> 4) << 3;
      const bf16* ap = hcur + (size_t)(omt + jj) * HID + kq;
      const bf16* bp = wob + (size_t)(ont + jj) * HID + kq;
      #pragma unroll
      for (int ks = wv * 8; ks < wv * 8 + 8; ++ks) {
        bf16x8 av = *(const bf16x8*)(ap + ks * 32);
        bf16x8 bv = *(const bf16x8*)(bp + ks * 32);
        oacc = __builtin_amdgcn_mfma_f32_16x16x32_bf16(av, bv, oacc, 0, 0, 0);
      }
      #pragma unroll
      for (int q = 0; q < 4; ++q)
        opart[wv][((lane >> 4) << 2) + q][jj] = oacc[q];   // row=(l>>4)*4+q, col=jj
    }
    __syncthreads();
    if (t >= 1) {
      const int orow = tid >> 4, ocol = tid & 15;
      float s = opart[0][orow][ocol] + opart[1][orow][ocol]
              + opart[2][orow][ocol] + opart[3][orow][ocol];
      obuf[orow][ocol][(t - 1) & 15] = s + bo;
    }

    // flush 16 buffered output steps (coalesced 64B runs into [b][o][t] layout)
    if ((t & 15) == 0 && t >= 16) {
      __syncthreads();
      const int orow = tid >> 4, ocol = tid & 15;
      float* dst = out + ((size_t)(omt + orow) * NCH + (ont + ocol)) * TLEN + (t - 16);
      #pragma unroll
      for (int s = 0; s < 16; ++s) dst[s] = obuf[orow][ocol][s];
    }

    if (t == TLEN) break;

    // gates GEMM: [128x64] = x_part + h[128x1024] @ W'[64x1024]^T
    f32x16 accA = xpA, accB = xpB;
    {
      const bf16* ap = hcur + (size_t)(wrow + l31) * HID + (lhi << 3);
      const char* wb = (const char*)wlds;
      const int base0 = l31 * 2048;
      const int sxor  = (l31 & 15) << 4;   // matches 4-bit staging swizzle
      const int kb4   = lhi << 4;
      #pragma unroll 16
      for (int ks = 0; ks < 64; ++ks) {
        bf16x8 av = *(const bf16x8*)(ap + ks * 16);
        const int ko = ((ks << 5) | kb4) ^ sxor;
        bf16x8 b0 = *(const bf16x8*)(wb + base0 + ko);
        bf16x8 b1 = *(const bf16x8*)(wb + base0 + 65536 + ko);
        accA = __builtin_amdgcn_mfma_f32_32x32x16_bf16(av, b0, accA, 0, 0, 0);
        accB = __builtin_amdgcn_mfma_f32_32x32x16_bf16(av, b1, accB, 0, 0, 0);
      }
    }

    // LSTM cell update. accA cols: i (l31<16) / f (l31>=16); accB: g / o.
    float s0[16], s1[16], u0[16], u1[16];
    #pragma unroll
    for (int q = 0; q < 16; ++q) {
      s0[q] = sigm(accA[q]);                       // sig(i) on low, sig(f) on high
      float a1 = accB[q];
      float sg = sigm(low ? 2.f * a1 : a1);
      s1[q] = low ? 2.f * sg - 1.f : sg;           // tanh(g) on low, sig(o) on high
    }
    #pragma unroll
    for (int q = 0; q < 16; ++q) {
      u0[q] = __shfl_xor(s0[q], 16);
      u1[q] = __shfl_xor(s1[q], 16);
    }

    // ---- h store: packed u32, agent-scope RELAXED atomic (sc1 -> LLC).
    //      No dirty L2 h lines => release needs no wbl2.
    {
      unsigned* const h32 = (unsigned*)hnxt;
      #pragma unroll
      for (int q = 0; q < 8; ++q) {
        float fg  = low ? u0[q]         : s0[q + 8];
        float ig  = low ? s0[q] * s1[q] : u0[q + 8] * u1[q + 8];
        float og  = low ? u1[q]         : s1[q + 8];
        float cn  = fg * creg[q] + ig;
        creg[q] = cn;
        float hv = og * (2.f * sigm(2.f * cn) - 1.f);
        unsigned v = (unsigned)f2bf(hv);
        unsigned p = (unsigned)__shfl_xor((int)v, 1);
        if (!(lane & 1)) {
          int rr = (q & 3) + ((q >> 2) << 3) + (lhi << 2) + (low ? 0 : 16);
          __hip_atomic_store(&h32[((size_t)(wrow + rr) << 9) + (jcol >> 1)],
                             v | (p << 16), __ATOMIC_RELAXED, __HIP_MEMORY_SCOPE_AGENT);
        }
      }
    }

    // ---- grid barrier: zero-wbl2 release + elected acquire (r10 acquire) ----
    // per-wave drain: sc1 store ack = LLC arrival; then block-wide sync.
    asm volatile("s_waitcnt vmcnt(0)" ::: "memory");
    __syncthreads();
    if (tid == 0) {
      unsigned old = __hip_atomic_fetch_add(xcdCnt, 1u, __ATOMIC_RELAXED, __HIP_MEMORY_SCOPE_AGENT);
      const bool lastx = !elect || (old == mypop * (unsigned)(t + 1) - 1u);
      if (lastx) {
        if (elect) {
          // all XCD-mates' h stores are LLC-visible (sc1 + their vmcnt drains
          // preceded their arrival adds). No fence needed. RELAXED add.
          __hip_atomic_fetch_add(gCnt, 1u, __ATOMIC_RELAXED, __HIP_MEMORY_SCOPE_AGENT);
        } else {
          __threadfence();   // degenerate-census fallback: conservative (r6)
          __hip_atomic_fetch_add(gCnt, 1u, __ATOMIC_RELEASE, __HIP_MEMORY_SCOPE_AGENT);
        }
      }
      if (!elect) {
        const unsigned tgt = NF * (unsigned)(t + 1);
        int it = 0;
        while (__hip_atomic_load(gCnt, __ATOMIC_RELAXED, __HIP_MEMORY_SCOPE_AGENT) < tgt) {
          __builtin_amdgcn_s_sleep(1);
          if ((++it & 255) == 0) __builtin_amdgcn_fence(__ATOMIC_ACQUIRE, "agent");
        }
      } else if (lastx) {
        // elected: poll gCnt for all XCDs, ONE agent acquire (inv; cheap),
        // then publish epoch via relaxed AGENT atomic (sc1 -> LLC).
        const unsigned tgt = (unsigned)nx * (unsigned)(t + 1);
        int it = 0;
        while (__hip_atomic_load(gCnt, __ATOMIC_RELAXED, __HIP_MEMORY_SCOPE_AGENT) < tgt) {
          __builtin_amdgcn_s_sleep(1);
          if ((++it & 255) == 0) __builtin_amdgcn_fence(__ATOMIC_ACQUIRE, "agent");
        }
        __builtin_amdgcn_fence(__ATOMIC_ACQUIRE, "agent");  // L1+L2 inv
        __hip_atomic_store(epochX, (unsigned)(t + 1), __ATOMIC_RELAXED, __HIP_MEMORY_SCOPE_AGENT);
      } else {
        // non-elected: spin on own-XCD epoch with relaxed AGENT loads (LLC).
        const unsigned want = (unsigned)(t + 1);
        int it = 0; bool ok = false;
        while (true) {
          if (__hip_atomic_load(epochX, __ATOMIC_RELAXED, __HIP_MEMORY_SCOPE_AGENT) >= want) { ok = true; break; }
          __builtin_amdgcn_s_sleep(1);
          if (++it > (1 << 18)) break;     // bounded: never hang
        }
        if (ok) {
          // L2 already inv'd by elected pre-publish; drop this CU's stale L1.
          asm volatile("buffer_inv" ::: "memory");
        } else {
          // timeout fallback: direct gCnt poll + full fence (conservative)
          const unsigned tgt = (unsigned)nx * (unsigned)(t + 1);
          int it2 = 0;
          while (__hip_atomic_load(gCnt, __ATOMIC_RELAXED, __HIP_MEMORY_SCOPE_AGENT) < tgt) {
            __builtin_amdgcn_s_sleep(1);
            if ((++it2 & 255) == 0) __builtin_amdgcn_fence(__ATOMIC_ACQUIRE, "agent");
          }
          __threadfence();
        }
      }
    }
    if (!elect) {
      if (tid < 64) __builtin_amdgcn_fence(__ATOMIC_ACQUIRE, "agent");
    }
    __syncthreads();
  }
}

extern "C" void kernel_launch(void* const* d_in, const int* in_sizes, int n_in,
                              void* d_out, int out_size, void* d_ws, size_t ws_size,
                              hipStream_t stream)
{
  const float* hid0  = (const float*)d_in[0];
  const float* inp0  = (const float*)d_in[1];
  const float* cell0 = (const float*)d_in[2];
  const float* W_ih  = (const float*)d_in[3];
  const float* W_hh  = (const float*)d_in[4];
  const float* b_ih  = (const float*)d_in[5];
  const float* b_hh  = (const float*)d_in[6];
  const float* W_out = (const float*)d_in[7];
  const float* b_out = (const float*)d_in[8];
  float* out = (float*)d_out;

  char* ws = (char*)d_ws;
  bf16* wp      = (bf16*)(ws + OFF_WP);
  bf16* wob     = (bf16*)(ws + OFF_WOB);
  bf16* hb0     = (bf16*)(ws + OFF_HB0);
  bf16* hb1     = (bf16*)(ws + OFF_HB1);
  float* xp     = (float*)(ws + OFF_XP);
  unsigned* bar = (unsigned*)(ws + OFF_BAR);

  prep_misc<<<512, 256, 0, stream>>>(hid0, W_out, hb0, wob, bar);
  prep_wp<<<4096, 256, 0, stream>>>(W_ih, W_hh, wp);
  prep_xp<<<512, 256, 0, stream>>>(inp0, W_ih, b_ih, b_hh, xp);

  void* args[] = { &wp, &wob, &xp, &cell0, &b_out, &hb0, &hb1, &out, &bar };
  hipError_t e = hipLaunchCooperativeKernel(lstm_main, dim3(256), dim3(256), args, 0u, stream);
  if (e != hipSuccess) {
    lstm_main<<<dim3(256), dim3(256), 0, stream>>>(wp, wob, xp, cell0, b_out,
                                                   hb0, hb1, out, bar);
  }
}